// Round 1
// baseline (586.091 us; speedup 1.0000x reference)
//
#include <hip/hip_runtime.h>
#include <hip/hip_bf16.h>
#include <stdint.h>

#define D 128
#define K2 256
#define K2P 264
#define SCAN_ITEMS 1024

typedef __attribute__((ext_vector_type(8))) short short8;
typedef __attribute__((ext_vector_type(4))) float f32x4;

__device__ inline float bf16lo(uint32_t u){ return __uint_as_float(u << 16); }
__device__ inline float bf16hi(uint32_t u){ return __uint_as_float(u & 0xffff0000u); }
__device__ inline unsigned short f2bf(float f){
    __hip_bfloat16 h = __float2bfloat16(f);
    union { __hip_bfloat16 h; unsigned short u; } cvt;
    cvt.h = h;
    return cvt.u;
}

// ---------- input fp32 -> bf16 ----------
__global__ void cvt_f32_bf16(const float* __restrict__ x, unsigned short* __restrict__ xb, int n8){
    int i = blockIdx.x * blockDim.x + threadIdx.x;
    if (i >= n8) return;
    const float4* p = reinterpret_cast<const float4*>(x) + (size_t)i * 2;
    float4 a = p[0], b = p[1];
    uint4 o;
    o.x = (uint32_t)f2bf(a.x) | ((uint32_t)f2bf(a.y) << 16);
    o.y = (uint32_t)f2bf(a.z) | ((uint32_t)f2bf(a.w) << 16);
    o.z = (uint32_t)f2bf(b.x) | ((uint32_t)f2bf(b.y) << 16);
    o.w = (uint32_t)f2bf(b.z) | ((uint32_t)f2bf(b.w) << 16);
    reinterpret_cast<uint4*>(xb)[i] = o;
}

// ---------- CSR build ----------
__global__ void count_deg(const int* __restrict__ dst, int* __restrict__ deg, int E){
    int e = blockIdx.x * 256 + threadIdx.x;
    if (e < E) atomicAdd(&deg[dst[e]], 1);
}

__global__ void scan_block_sums(const int* __restrict__ deg, int* __restrict__ part, int n){
    __shared__ int s[256];
    int t = threadIdx.x;
    int base = blockIdx.x * SCAN_ITEMS + t * 4;
    int v = 0;
    #pragma unroll
    for (int j = 0; j < 4; j++){ int i = base + j; if (i < n) v += deg[i]; }
    s[t] = v; __syncthreads();
    for (int o = 128; o > 0; o >>= 1){
        if (t < o) s[t] += s[t + o];
        __syncthreads();
    }
    if (t == 0) part[blockIdx.x] = s[0];
}

__global__ void scan_partials(int* part, int nb){
    __shared__ int s[256];
    int t = threadIdx.x;
    int v = (t < nb) ? part[t] : 0;
    s[t] = v; __syncthreads();
    for (int o = 1; o < 256; o <<= 1){
        int x = (t >= o) ? s[t - o] : 0;
        __syncthreads();
        s[t] += x;
        __syncthreads();
    }
    if (t < nb) part[t] = s[t] - v;   // exclusive
}

__global__ void scan_write(const int* __restrict__ deg, const int* __restrict__ part,
                           int* __restrict__ roff, int* __restrict__ fill, int n, int E){
    __shared__ int s[256];
    int t = threadIdx.x;
    int base = blockIdx.x * SCAN_ITEMS + t * 4;
    int loc[4]; int sum = 0;
    #pragma unroll
    for (int j = 0; j < 4; j++){
        int i = base + j;
        loc[j] = sum;
        int d = (i < n) ? deg[i] : 0;
        sum += d;
    }
    s[t] = sum; __syncthreads();
    int own = sum;
    for (int o = 1; o < 256; o <<= 1){
        int x = (t >= o) ? s[t - o] : 0;
        __syncthreads();
        s[t] += x;
        __syncthreads();
    }
    int tbase = part[blockIdx.x] + s[t] - own;
    #pragma unroll
    for (int j = 0; j < 4; j++){
        int i = base + j;
        if (i < n){ int v = tbase + loc[j]; roff[i] = v; fill[i] = v; }
    }
    if (blockIdx.x == 0 && t == 0) roff[n] = E;
}

__global__ void fill_csr(const int* __restrict__ src, const int* __restrict__ dst,
                         int* __restrict__ fill, int* __restrict__ csr, int E){
    int e = blockIdx.x * 256 + threadIdx.x;
    if (e < E){
        int p = atomicAdd(&fill[dst[e]], 1);
        csr[p] = src[e];
    }
}

// ---------- segment-mean aggregation (quarter-wave per node) ----------
__global__ void aggregate(const unsigned short* __restrict__ hb, const int* __restrict__ roff,
                          const int* __restrict__ csr, unsigned short* __restrict__ aggb, int n){
    int sub = threadIdx.x >> 4, li = threadIdx.x & 15;
    int v = blockIdx.x * 16 + sub;
    if (v >= n) return;
    int s0 = roff[v], s1 = roff[v + 1];
    float acc[8] = {0.f,0.f,0.f,0.f,0.f,0.f,0.f,0.f};
    for (int e = s0; e < s1; e++){
        int s = csr[e];
        uint4 q = *reinterpret_cast<const uint4*>(hb + (size_t)s * D + li * 8);
        acc[0] += bf16lo(q.x); acc[1] += bf16hi(q.x);
        acc[2] += bf16lo(q.y); acc[3] += bf16hi(q.y);
        acc[4] += bf16lo(q.z); acc[5] += bf16hi(q.z);
        acc[6] += bf16lo(q.w); acc[7] += bf16hi(q.w);
    }
    float inv = 1.0f / fmaxf((float)(s1 - s0), 1.0f);
    uint4 o;
    o.x = (uint32_t)f2bf(acc[0]*inv) | ((uint32_t)f2bf(acc[1]*inv) << 16);
    o.y = (uint32_t)f2bf(acc[2]*inv) | ((uint32_t)f2bf(acc[3]*inv) << 16);
    o.z = (uint32_t)f2bf(acc[4]*inv) | ((uint32_t)f2bf(acc[5]*inv) << 16);
    o.w = (uint32_t)f2bf(acc[6]*inv) | ((uint32_t)f2bf(acc[7]*inv) << 16);
    *reinterpret_cast<uint4*>(aggb + (size_t)v * D + li * 8) = o;
}

// ---------- fused SAGE GEMM: out = relu?( [agg|x] @ [Wl;Wr] + b ) ----------
template<int DOUT, bool RELU, bool OUTBF>
__global__ __launch_bounds__(256, 2) void sage_gemm(
    const unsigned short* __restrict__ aggb, const unsigned short* __restrict__ xb,
    const float* __restrict__ Wl, const float* __restrict__ Wr, const float* __restrict__ bias,
    unsigned short* __restrict__ outb, float* __restrict__ outf, int n)
{
    __shared__ __align__(16) unsigned short bt[DOUT * K2P];
    int tid = threadIdx.x;

    // stage weights transposed: bt[col][k] = Wcat[k][col], fp32 -> bf16
    for (int idx = tid; idx < DOUT * K2; idx += 256){
        int j = idx % DOUT, k = idx / DOUT;        // coalesced over j
        float w = (k < 128) ? Wl[k * DOUT + j] : Wr[(k - 128) * DOUT + j];
        bt[j * K2P + k] = f2bf(w);
    }
    __syncthreads();

    int wave = tid >> 6, lane = tid & 63;
    constexpr int CF = DOUT / 64;                  // col frags per wave
    int colbase = wave * 16 * CF;
    int rbase = blockIdx.x * 64;
    int lrow = lane & 15, lk = (lane >> 4) * 8;

    f32x4 acc[4][CF];
    #pragma unroll
    for (int fr = 0; fr < 4; fr++)
        #pragma unroll
        for (int cf = 0; cf < CF; cf++)
            acc[fr][cf] = (f32x4){0.f, 0.f, 0.f, 0.f};

    int r[4];
    #pragma unroll
    for (int fr = 0; fr < 4; fr++) r[fr] = min(rbase + fr * 16 + lrow, n - 1);

    #pragma unroll
    for (int kk = 0; kk < 8; kk++){
        const unsigned short* A = (kk < 4) ? aggb : xb;
        int k0 = (kk & 3) * 32 + lk;
        short8 a[4];
        #pragma unroll
        for (int fr = 0; fr < 4; fr++)
            a[fr] = *reinterpret_cast<const short8*>(A + (size_t)r[fr] * D + k0);
        #pragma unroll
        for (int cf = 0; cf < CF; cf++){
            short8 b = *reinterpret_cast<const short8*>(&bt[(colbase + cf * 16 + lrow) * K2P + kk * 32 + lk]);
            #pragma unroll
            for (int fr = 0; fr < 4; fr++)
                acc[fr][cf] = __builtin_amdgcn_mfma_f32_16x16x32_bf16(a[fr], b, acc[fr][cf], 0, 0, 0);
        }
    }

    // epilogue: bias (+relu), store
    #pragma unroll
    for (int fr = 0; fr < 4; fr++){
        int rowb = rbase + fr * 16 + (lane >> 4) * 4;
        #pragma unroll
        for (int cf = 0; cf < CF; cf++){
            int col = colbase + cf * 16 + (lane & 15);
            float bv = bias[col];
            #pragma unroll
            for (int reg = 0; reg < 4; reg++){
                int row = rowb + reg;
                if (row < n){
                    float vv = acc[fr][cf][reg] + bv;
                    if (RELU) vv = fmaxf(vv, 0.f);
                    if (OUTBF) outb[(size_t)row * DOUT + col] = f2bf(vv);
                    else       outf[(size_t)row * DOUT + col] = vv;
                }
            }
        }
    }
}

extern "C" void kernel_launch(void* const* d_in, const int* in_sizes, int n_in,
                              void* d_out, int out_size, void* d_ws, size_t ws_size,
                              hipStream_t stream)
{
    const float* x   = (const float*)d_in[0];
    const int*   ei  = (const int*)d_in[1];
    const float* Wl0 = (const float*)d_in[2];
    const float* Wr0 = (const float*)d_in[3];
    const float* b0  = (const float*)d_in[4];
    const float* Wl1 = (const float*)d_in[5];
    const float* Wr1 = (const float*)d_in[6];
    const float* b1  = (const float*)d_in[7];
    const float* Wl2 = (const float*)d_in[8];
    const float* Wr2 = (const float*)d_in[9];
    const float* b2  = (const float*)d_in[10];

    int N = in_sizes[0] / D;
    int E = in_sizes[1] / 2;
    const int* src = ei;
    const int* dst = ei + E;

    char* ws = (char*)d_ws;
    size_t off = 0;
    auto alloc = [&](size_t bytes) -> void* {
        void* p = ws + off;
        off = (off + bytes + 255) & ~(size_t)255;
        return p;
    };
    int* deg  = (int*)alloc((size_t)N * 4);
    int* roff = (int*)alloc(((size_t)N + 1) * 4);
    int* fill = (int*)alloc((size_t)N * 4);
    int* part = (int*)alloc(256 * 4);
    int* csr  = (int*)alloc((size_t)E * 4);
    unsigned short* xb  = (unsigned short*)alloc((size_t)N * D * 2);
    unsigned short* h0  = (unsigned short*)alloc((size_t)N * D * 2);
    unsigned short* agg = (unsigned short*)alloc((size_t)N * D * 2);
    unsigned short* h1  = xb;   // alias: x no longer needed once layer1 runs

    hipMemsetAsync(deg, 0, (size_t)N * 4, stream);

    int n8 = N * D / 8;
    cvt_f32_bf16<<<(n8 + 255) / 256, 256, 0, stream>>>(x, xb, n8);

    count_deg<<<(E + 255) / 256, 256, 0, stream>>>(dst, deg, E);
    int NB = (N + SCAN_ITEMS - 1) / SCAN_ITEMS;
    scan_block_sums<<<NB, 256, 0, stream>>>(deg, part, N);
    scan_partials<<<1, 256, 0, stream>>>(part, NB);
    scan_write<<<NB, 256, 0, stream>>>(deg, part, roff, fill, N, E);
    fill_csr<<<(E + 255) / 256, 256, 0, stream>>>(src, dst, fill, csr, E);

    int gAgg = (N + 15) / 16;
    int gGemm = (N + 63) / 64;

    // layer 0
    aggregate<<<gAgg, 256, 0, stream>>>(xb, roff, csr, agg, N);
    sage_gemm<128, true, true><<<gGemm, 256, 0, stream>>>(agg, xb, Wl0, Wr0, b0, h0, nullptr, N);
    // layer 1
    aggregate<<<gAgg, 256, 0, stream>>>(h0, roff, csr, agg, N);
    sage_gemm<128, true, true><<<gGemm, 256, 0, stream>>>(agg, h0, Wl1, Wr1, b1, h1, nullptr, N);
    // layer 2
    aggregate<<<gAgg, 256, 0, stream>>>(h1, roff, csr, agg, N);
    sage_gemm<64, false, false><<<gGemm, 256, 0, stream>>>(agg, h1, Wl2, Wr2, b2, nullptr, (float*)d_out, N);
}